// Round 1
// baseline (1324.324 us; speedup 1.0000x reference)
//
#include <hip/hip_runtime.h>
#include <hip/hip_bf16.h>
#include <cstdint>

#define HD 256
#define NHEADS 8
#define NB 256
#define SL 64
#define NN 16384
#define NE 131072
#define NTOT (NE + NN)   // 147456

typedef float floatx4 __attribute__((ext_vector_type(4)));
typedef short shortx8 __attribute__((ext_vector_type(8)));
typedef unsigned short ushortx8 __attribute__((ext_vector_type(8)));
typedef unsigned short ushortx4 __attribute__((ext_vector_type(4)));

__device__ __forceinline__ unsigned short f2bf(float f) {
    union { float f; unsigned u; } a; a.f = f;
    unsigned r = a.u + 0x7fffu + ((a.u >> 16) & 1u);
    return (unsigned short)(r >> 16);
}
__device__ __forceinline__ float bf2f(unsigned short b) {
    union { unsigned u; float f; } a; a.u = ((unsigned)b) << 16;
    return a.f;
}

// ---------------- conversions ----------------

__global__ void k_cast_bf16(const float* __restrict__ in, unsigned short* __restrict__ out, int n4) {
    int i = blockIdx.x * 256 + threadIdx.x;
    if (i >= n4) return;
    float4 v = ((const float4*)in)[i];
    ushortx4 o;
    o[0] = f2bf(v.x); o[1] = f2bf(v.y); o[2] = f2bf(v.z); o[3] = f2bf(v.w);
    *(ushortx4*)&out[i * 4] = o;
}

// out[n][k] = bf16(in[k][n]); in is K x N fp32. grid (N/32, K/32), block (32,8)
__global__ void k_transpose_bf16(const float* __restrict__ in, unsigned short* __restrict__ out,
                                 int K, int N) {
    __shared__ float t[32][33];
    int nb = blockIdx.x * 32, kb = blockIdx.y * 32;
    int tx = threadIdx.x, ty = threadIdx.y;
#pragma unroll
    for (int i = 0; i < 4; ++i) {
        int k = kb + ty + i * 8;
        t[ty + i * 8][tx] = in[(size_t)k * N + nb + tx];
    }
    __syncthreads();
#pragma unroll
    for (int i = 0; i < 4; ++i) {
        int nrow = nb + ty + i * 8;
        out[(size_t)nrow * K + kb + tx] = f2bf(t[tx][ty + i * 8]);
    }
}

__global__ void k_add2(const float* __restrict__ a, const float* __restrict__ b,
                       float* __restrict__ o, int n) {
    int i = blockIdx.x * 256 + threadIdx.x;
    if (i < n) o[i] = a[i] + b[i];
}

// x_b[n][d] = bf16(emb[x_ids[n]][d]), row 0 of emb forced to 0
__global__ void k_gather_x(const int* __restrict__ ids, const float* __restrict__ emb,
                           unsigned short* __restrict__ xb) {
    int i = blockIdx.x * 256 + threadIdx.x;   // over NN*64
    int n = i >> 6, d4 = (i & 63) << 2;
    int id = ids[n];
    float4 v = make_float4(0.f, 0.f, 0.f, 0.f);
    if (id != 0) v = *(const float4*)&emb[(size_t)id * HD + d4];
    ushortx4 o;
    o[0] = f2bf(v.x); o[1] = f2bf(v.y); o[2] = f2bf(v.z); o[3] = f2bf(v.w);
    *(ushortx4*)&xb[(size_t)n * HD + d4] = o;
}

// ---------------- GEMM: C(MxN) = A(MxK bf16) * B^T  (B given as N x K bf16) ----------------
// M % 128 == 0, K % 32 == 0; N masked. 128x128 tile, 4 waves of 64x64, 16x16x32 MFMA.

template <bool OUT_BF16, bool HAS_BIAS>
__global__ __launch_bounds__(256, 2) void k_gemm_bt(
    const unsigned short* __restrict__ A, const unsigned short* __restrict__ B,
    void* __restrict__ C, const float* __restrict__ bias, int M, int Nn, int K) {
    constexpr int LDT = 56;  // 112B row stride: 16B aligned, 2-way-max banks
    __shared__ unsigned short As[128 * LDT];
    __shared__ unsigned short Bs[128 * LDT];
    int tid = threadIdx.x;
    int wave = tid >> 6, lane = tid & 63;
    int q = lane >> 4, c16 = lane & 15;
    long m0 = (long)blockIdx.x * 128;
    long n0 = (long)blockIdx.y * 128;
    int wm = (wave & 1) << 6, wn = (wave >> 1) << 6;
    floatx4 acc[4][4] = {};
    int lrow = tid >> 2;
    int lk = (tid & 3) << 3;
    const unsigned short* Arow0 = A + (m0 + lrow) * K + lk;
    const unsigned short* Arow1 = A + (m0 + 64 + lrow) * K + lk;
    long nb0 = n0 + lrow;      if (nb0 >= Nn) nb0 = Nn - 1;
    long nb1 = n0 + 64 + lrow; if (nb1 >= Nn) nb1 = Nn - 1;
    const unsigned short* Brow0 = B + nb0 * K + lk;
    const unsigned short* Brow1 = B + nb1 * K + lk;

    for (int k0 = 0; k0 < K; k0 += 32) {
        ushortx8 a0 = *(const ushortx8*)(Arow0 + k0);
        ushortx8 a1 = *(const ushortx8*)(Arow1 + k0);
        ushortx8 b0 = *(const ushortx8*)(Brow0 + k0);
        ushortx8 b1 = *(const ushortx8*)(Brow1 + k0);
        __syncthreads();
        *(ushortx8*)&As[lrow * LDT + lk] = a0;
        *(ushortx8*)&As[(64 + lrow) * LDT + lk] = a1;
        *(ushortx8*)&Bs[lrow * LDT + lk] = b0;
        *(ushortx8*)&Bs[(64 + lrow) * LDT + lk] = b1;
        __syncthreads();
        shortx8 af[4], bfr[4];
#pragma unroll
        for (int mt = 0; mt < 4; ++mt)
            af[mt] = *(const shortx8*)&As[(wm + mt * 16 + c16) * LDT + q * 8];
#pragma unroll
        for (int nt = 0; nt < 4; ++nt)
            bfr[nt] = *(const shortx8*)&Bs[(wn + nt * 16 + c16) * LDT + q * 8];
#pragma unroll
        for (int mt = 0; mt < 4; ++mt)
#pragma unroll
            for (int nt = 0; nt < 4; ++nt)
                acc[mt][nt] = __builtin_amdgcn_mfma_f32_16x16x32_bf16(af[mt], bfr[nt], acc[mt][nt], 0, 0, 0);
    }
#pragma unroll
    for (int mt = 0; mt < 4; ++mt) {
        long row_base = m0 + wm + mt * 16 + q * 4;
#pragma unroll
        for (int nt = 0; nt < 4; ++nt) {
            long col = n0 + wn + nt * 16 + c16;
            if (col >= Nn) continue;
            float bv = HAS_BIAS ? bias[col] : 0.0f;
#pragma unroll
            for (int r = 0; r < 4; ++r) {
                float v = acc[mt][nt][r] + bv;
                long idx = (row_base + r) * (long)Nn + col;
                if (OUT_BF16) ((unsigned short*)C)[idx] = f2bf(v);
                else          ((float*)C)[idx] = v;
            }
        }
    }
}

// ---------------- attention dots ----------------

// block per node, 256 threads; h1b: NN x 2048 bf16; att flat 2048
__global__ void k_alpha1(const unsigned short* __restrict__ h1b, const float* __restrict__ asrc,
                         const float* __restrict__ adst, float* __restrict__ als,
                         float* __restrict__ ald) {
    int n = blockIdx.x, t = threadIdx.x;
    ushortx8 hv = *(const ushortx8*)&h1b[(size_t)n * 2048 + t * 8];
    float s = 0.f, d = 0.f;
#pragma unroll
    for (int j = 0; j < 8; ++j) {
        float f = bf2f(hv[j]);
        s += f * asrc[t * 8 + j];
        d += f * adst[t * 8 + j];
    }
    for (int o = 16; o; o >>= 1) { s += __shfl_down(s, o, 32); d += __shfl_down(d, o, 32); }
    if ((t & 31) == 0) { als[n * 8 + (t >> 5)] = s; ald[n * 8 + (t >> 5)] = d; }
}

// block per node, 64 threads; x2b: NN x 256 bf16; att flat 256
__global__ void k_alpha2(const unsigned short* __restrict__ x2b, const float* __restrict__ asrc,
                         const float* __restrict__ adst, float* __restrict__ als,
                         float* __restrict__ ald) {
    int n = blockIdx.x, t = threadIdx.x;
    ushortx4 hv = *(const ushortx4*)&x2b[(size_t)n * 256 + t * 4];
    float s = 0.f, d = 0.f;
#pragma unroll
    for (int j = 0; j < 4; ++j) {
        float f = bf2f(hv[j]);
        s += f * asrc[t * 4 + j];
        d += f * adst[t * 4 + j];
    }
    for (int o = 32; o; o >>= 1) { s += __shfl_down(s, o, 64); d += __shfl_down(d, o, 64); }
    if (t == 0) { als[n] = s; ald[n] = d; }
}

// ---------------- CSR build ----------------

__global__ void k_deg_init(int* __restrict__ deg) {
    int i = blockIdx.x * 256 + threadIdx.x;
    if (i < NN) deg[i] = 1;   // self loop
}
__global__ void k_deg_count(const int* __restrict__ ei, int* __restrict__ deg) {
    int e = blockIdx.x * 256 + threadIdx.x;
    if (e < NE) atomicAdd(&deg[ei[NE + e]], 1);
}
__global__ void k_scan(const int* __restrict__ deg, int* __restrict__ row_start,
                       int* __restrict__ cursor) {
    __shared__ int s[1024];
    int t = threadIdx.x;
    int base = t * 16;
    int loc[16]; int sum = 0;
#pragma unroll
    for (int i = 0; i < 16; ++i) { loc[i] = deg[base + i]; sum += loc[i]; }
    s[t] = sum;
    __syncthreads();
    for (int o = 1; o < 1024; o <<= 1) {
        int v = (t >= o) ? s[t - o] : 0;
        __syncthreads();
        s[t] += v;
        __syncthreads();
    }
    int ex = s[t] - sum;
#pragma unroll
    for (int i = 0; i < 16; ++i) {
        row_start[base + i] = ex;
        cursor[base + i] = ex;
        ex += loc[i];
    }
    if (t == 0) row_start[NN] = NTOT;
}
__global__ void k_fill(const int* __restrict__ ei, int* __restrict__ cursor,
                       int* __restrict__ csr_src) {
    int e = blockIdx.x * 256 + threadIdx.x;
    if (e >= NTOT) return;
    int s, d;
    if (e < NE) { s = ei[e]; d = ei[NE + e]; }
    else        { s = e - NE; d = s; }
    int p = atomicAdd(&cursor[d], 1);
    csr_src[p] = s;
}

// ---------------- GAT aggregation ----------------

// block per dst node, 256 threads (8 heads x 32 lanes); 8 cols of 256/head per thread
__global__ __launch_bounds__(256) void k_agg1(
    const int* __restrict__ row_start, const int* __restrict__ csr_src,
    const float* __restrict__ als, const float* __restrict__ ald,
    const unsigned short* __restrict__ h1b, const float* __restrict__ b1,
    unsigned short* __restrict__ out1b) {
    int n = blockIdx.x, t = threadIdx.x;
    int rs = row_start[n];
    int deg = row_start[n + 1] - rs;
    __shared__ float sm[8], sz[8], sad[8];
    if (t < 8) sad[t] = ald[n * 8 + t];
    __syncthreads();
    int hh = t >> 5, ii = t & 31;
    float adh = sad[hh];
    float lm = -1e30f;
    for (int i = ii; i < deg; i += 32) {
        int s = csr_src[rs + i];
        float e = als[s * 8 + hh] + adh;
        e = e >= 0.f ? e : 0.2f * e;
        lm = fmaxf(lm, e);
    }
    for (int o = 16; o; o >>= 1) lm = fmaxf(lm, __shfl_down(lm, o, 32));
    if (ii == 0) sm[hh] = lm;
    __syncthreads();
    float mh = sm[hh];
    float lz = 0.f;
    for (int i = ii; i < deg; i += 32) {
        int s = csr_src[rs + i];
        float e = als[s * 8 + hh] + adh;
        e = e >= 0.f ? e : 0.2f * e;
        lz += expf(e - mh);
    }
    for (int o = 16; o; o >>= 1) lz += __shfl_down(lz, o, 32);
    if (ii == 0) sz[hh] = lz;
    __syncthreads();
    float inv_z = 1.0f / (sz[hh] + 1e-16f);
    float acc[8] = {0.f, 0.f, 0.f, 0.f, 0.f, 0.f, 0.f, 0.f};
    for (int i = 0; i < deg; ++i) {
        int s = csr_src[rs + i];
        float e = als[s * 8 + hh] + adh;
        e = e >= 0.f ? e : 0.2f * e;
        float w = expf(e - mh) * inv_z;
        ushortx8 hv = *(const ushortx8*)&h1b[(size_t)s * 2048 + t * 8];
#pragma unroll
        for (int j = 0; j < 8; ++j) acc[j] += w * bf2f(hv[j]);
    }
    ushortx8 o8;
#pragma unroll
    for (int j = 0; j < 8; ++j) {
        float v = acc[j] + b1[t * 8 + j];
        v = v > 0.f ? v : expm1f(v);   // elu
        o8[j] = f2bf(v);
    }
    *(ushortx8*)&out1b[(size_t)n * 2048 + t * 8] = o8;
}

// block per dst node, 64 threads; 1 head, 4 cols/thread
__global__ void k_agg2(const int* __restrict__ row_start, const int* __restrict__ csr_src,
                       const float* __restrict__ als, const float* __restrict__ ald,
                       const unsigned short* __restrict__ x2b, const float* __restrict__ b2,
                       unsigned short* __restrict__ out2b) {
    int n = blockIdx.x, t = threadIdx.x;
    int rs = row_start[n];
    int deg = row_start[n + 1] - rs;
    float adn = ald[n];
    float lm = -1e30f;
    for (int i = t; i < deg; i += 64) {
        float e = als[csr_src[rs + i]] + adn;
        e = e >= 0.f ? e : 0.2f * e;
        lm = fmaxf(lm, e);
    }
    for (int o = 32; o; o >>= 1) lm = fmaxf(lm, __shfl_down(lm, o, 64));
    float mh = __shfl(lm, 0, 64);
    float lz = 0.f;
    for (int i = t; i < deg; i += 64) {
        float e = als[csr_src[rs + i]] + adn;
        e = e >= 0.f ? e : 0.2f * e;
        lz += expf(e - mh);
    }
    for (int o = 32; o; o >>= 1) lz += __shfl_down(lz, o, 64);
    float zz = __shfl(lz, 0, 64);
    float inv_z = 1.0f / (zz + 1e-16f);
    float acc[4] = {0.f, 0.f, 0.f, 0.f};
    for (int i = 0; i < deg; ++i) {
        int s = csr_src[rs + i];
        float e = als[s] + adn;
        e = e >= 0.f ? e : 0.2f * e;
        float w = expf(e - mh) * inv_z;
        ushortx4 hv = *(const ushortx4*)&x2b[(size_t)s * 256 + t * 4];
#pragma unroll
        for (int j = 0; j < 4; ++j) acc[j] += w * bf2f(hv[j]);
    }
    ushortx4 o4;
#pragma unroll
    for (int j = 0; j < 4; ++j) o4[j] = f2bf(acc[j] + b2[t * 4 + j]);
    *(ushortx4*)&out2b[(size_t)n * 256 + t * 4] = o4;
}

// ---------------- LSTM recurrence ----------------
// 16 blocks x 256 threads; block owns 16 batch rows, loops 64 steps.
// Wave w handles cols w*64..w*64+63 of EACH gate group -> c/h update fully in-register.

__global__ __launch_bounds__(256, 1) void k_lstm(const float* __restrict__ Xg,
                                                 const unsigned short* __restrict__ Whhb,
                                                 unsigned short* __restrict__ hTb) {
    constexpr int LDH = 264;  // bf16 row stride: 528B, 16B-aligned, 2-way-max banks
    __shared__ unsigned short hb[16 * LDH];
    int tid = threadIdx.x;
    int wave = tid >> 6, lane = tid & 63;
    int q = lane >> 4, c16 = lane & 15;
    int r0 = blockIdx.x * 16;
    for (int i = tid; i < 16 * LDH; i += 256) hb[i] = 0;
    float cst[4][4] = {};
    __syncthreads();
    for (int t = 0; t < SL; ++t) {
        floatx4 acc[4][4] = {};  // [gate][ct2]
        for (int k0 = 0; k0 < 256; k0 += 32) {
            shortx8 a = *(const shortx8*)&hb[c16 * LDH + k0 + q * 8];
#pragma unroll
            for (int g = 0; g < 4; ++g) {
#pragma unroll
                for (int ct2 = 0; ct2 < 4; ++ct2) {
                    int col = g * 256 + wave * 64 + ct2 * 16 + c16;
                    shortx8 b = *(const shortx8*)&Whhb[(size_t)col * 256 + k0 + q * 8];
                    acc[g][ct2] = __builtin_amdgcn_mfma_f32_16x16x32_bf16(a, b, acc[g][ct2], 0, 0, 0);
                }
            }
        }
        __syncthreads();  // all hb reads done
#pragma unroll
        for (int ct2 = 0; ct2 < 4; ++ct2) {
            int colb = wave * 64 + ct2 * 16 + c16;
#pragma unroll
            for (int r = 0; r < 4; ++r) {
                int b = r0 + q * 4 + r;
                const float* xg = Xg + ((size_t)b * SL + t) * 1024;
                float gi = acc[0][ct2][r] + xg[colb];
                float gf = acc[1][ct2][r] + xg[256 + colb];
                float gg = acc[2][ct2][r] + xg[512 + colb];
                float go = acc[3][ct2][r] + xg[768 + colb];
                float si = 1.f / (1.f + expf(-gi));
                float sf = 1.f / (1.f + expf(-gf));
                float so = 1.f / (1.f + expf(-go));
                float c = sf * cst[ct2][r] + si * tanhf(gg);
                cst[ct2][r] = c;
                float h = so * tanhf(c);
                hb[(q * 4 + r) * LDH + colb] = f2bf(h);
            }
        }
        __syncthreads();  // hb writes visible
    }
    for (int i = tid; i < 16 * 256; i += 256) {
        int row = i >> 8, col = i & 255;
        hTb[(size_t)(r0 + row) * 256 + col] = hb[row * LDH + col];
    }
}

// ---------------- launch ----------------

extern "C" void kernel_launch(void* const* d_in, const int* in_sizes, int n_in,
                              void* d_out, int out_size, void* d_ws, size_t ws_size,
                              hipStream_t stream) {
    const int*   x_ids = (const int*)d_in[0];
    const int*   ei    = (const int*)d_in[1];
    const float* emb   = (const float*)d_in[3];
    const float* W1    = (const float*)d_in[4];
    const float* as1w  = (const float*)d_in[5];
    const float* ad1w  = (const float*)d_in[6];
    const float* b1    = (const float*)d_in[7];
    const float* W2    = (const float*)d_in[8];
    const float* as2w  = (const float*)d_in[9];
    const float* ad2w  = (const float*)d_in[10];
    const float* b2    = (const float*)d_in[11];
    const float* Wih   = (const float*)d_in[12];
    const float* Whh   = (const float*)d_in[13];
    const float* bih   = (const float*)d_in[14];
    const float* bhh   = (const float*)d_in[15];
    const float* Wp    = (const float*)d_in[16];
    const float* bp    = (const float*)d_in[17];

    char* ws = (char*)d_ws;
    size_t off = 0;
    auto alloc = [&](size_t bytes) -> void* {
        void* p = ws + off;
        off += (bytes + 255) & ~(size_t)255;
        return p;
    };
    unsigned short* h1b   = (unsigned short*)alloc((size_t)NN * 2048 * 2);  // 67MB; reused as Xg
    float*          Xg    = (float*)h1b;                                     // NN*1024*4 == same bytes
    unsigned short* out1b = (unsigned short*)alloc((size_t)NN * 2048 * 2);
    unsigned short* xb    = (unsigned short*)alloc((size_t)NN * 256 * 2);
    unsigned short* x2b   = (unsigned short*)alloc((size_t)NN * 256 * 2);
    unsigned short* out2b = (unsigned short*)alloc((size_t)NN * 256 * 2);
    unsigned short* W1t   = (unsigned short*)alloc((size_t)2048 * 256 * 2);
    unsigned short* W2t   = (unsigned short*)alloc((size_t)256 * 2048 * 2);
    unsigned short* Wihb  = (unsigned short*)alloc((size_t)1024 * 256 * 2);
    unsigned short* Whhb  = (unsigned short*)alloc((size_t)1024 * 256 * 2);
    unsigned short* Wpb   = (unsigned short*)alloc((size_t)37000 * 256 * 2);
    float*          bb    = (float*)alloc(1024 * 4);
    float*          als1  = (float*)alloc((size_t)NN * 8 * 4);
    float*          ald1  = (float*)alloc((size_t)NN * 8 * 4);
    float*          als2  = (float*)alloc((size_t)NN * 4);
    float*          ald2  = (float*)alloc((size_t)NN * 4);
    unsigned short* hTb   = (unsigned short*)alloc((size_t)256 * 256 * 2);
    int* deg       = (int*)alloc((size_t)NN * 4);
    int* row_start = (int*)alloc((size_t)(NN + 1) * 4);
    int* cursor    = (int*)alloc((size_t)NN * 4);
    int* csr_src   = (int*)alloc((size_t)NTOT * 4);
    (void)ws_size; (void)in_sizes; (void)n_in; (void)out_size;

    // weight prep
    k_transpose_bf16<<<dim3(2048 / 32, 256 / 32), dim3(32, 8), 0, stream>>>(W1, W1t, 256, 2048);
    k_transpose_bf16<<<dim3(256 / 32, 2048 / 32), dim3(32, 8), 0, stream>>>(W2, W2t, 2048, 256);
    k_cast_bf16<<<(262144 / 4 + 255) / 256, 256, 0, stream>>>(Wih, Wihb, 262144 / 4);
    k_cast_bf16<<<(262144 / 4 + 255) / 256, 256, 0, stream>>>(Whh, Whhb, 262144 / 4);
    k_cast_bf16<<<(9472000 / 4 + 255) / 256, 256, 0, stream>>>(Wp, Wpb, 9472000 / 4);
    k_add2<<<4, 256, 0, stream>>>(bih, bhh, bb, 1024);

    // CSR (independent of features)
    k_deg_init<<<NN / 256, 256, 0, stream>>>(deg);
    k_deg_count<<<NE / 256, 256, 0, stream>>>(ei, deg);
    k_scan<<<1, 1024, 0, stream>>>(deg, row_start, cursor);
    k_fill<<<(NTOT + 255) / 256, 256, 0, stream>>>(ei, cursor, csr_src);

    // embedding gather
    k_gather_x<<<NN * 64 / 256, 256, 0, stream>>>(x_ids, emb, xb);

    // GAT layer 1
    k_gemm_bt<true, false><<<dim3(NN / 128, 2048 / 128), 256, 0, stream>>>(
        xb, W1t, h1b, nullptr, NN, 2048, 256);
    k_alpha1<<<NN, 256, 0, stream>>>(h1b, as1w, ad1w, als1, ald1);
    k_agg1<<<NN, 256, 0, stream>>>(row_start, csr_src, als1, ald1, h1b, b1, out1b);

    // GAT layer 2
    k_gemm_bt<true, false><<<dim3(NN / 128, 256 / 128), 256, 0, stream>>>(
        out1b, W2t, x2b, nullptr, NN, 256, 2048);
    k_alpha2<<<NN, 64, 0, stream>>>(x2b, as2w, ad2w, als2, ald2);
    k_agg2<<<NN, 64, 0, stream>>>(row_start, csr_src, als2, ald2, x2b, b2, out2b);

    // LSTM: Xg = out2 @ Wih^T + (bih + bhh)   (overwrites h1b region — h1b is dead)
    k_gemm_bt<false, true><<<dim3(NN / 128, 1024 / 128), 256, 0, stream>>>(
        out2b, Wihb, Xg, bb, NN, 1024, 256);
    k_lstm<<<16, 256, 0, stream>>>(Xg, Whhb, hTb);

    // final projection
    k_gemm_bt<false, true><<<dim3(256 / 128, (37000 + 127) / 128), 256, 0, stream>>>(
        hTb, Wpb, (float*)d_out, bp, 256, 37000, 256);
}

// Round 2
// 835.268 us; speedup vs baseline: 1.5855x; 1.5855x over previous
//
#include <hip/hip_runtime.h>
#include <hip/hip_bf16.h>
#include <cstdint>

#define HD 256
#define NHEADS 8
#define NB 256
#define SL 64
#define NN 16384
#define NE 131072
#define NTOT (NE + NN)   // 147456

typedef float floatx4 __attribute__((ext_vector_type(4)));
typedef short shortx8 __attribute__((ext_vector_type(8)));
typedef unsigned short ushortx8 __attribute__((ext_vector_type(8)));
typedef unsigned short ushortx4 __attribute__((ext_vector_type(4)));

__device__ __forceinline__ unsigned short f2bf(float f) {
    union { float f; unsigned u; } a; a.f = f;
    unsigned r = a.u + 0x7fffu + ((a.u >> 16) & 1u);
    return (unsigned short)(r >> 16);
}
__device__ __forceinline__ float bf2f(unsigned short b) {
    union { unsigned u; float f; } a; a.u = ((unsigned)b) << 16;
    return a.f;
}

// ---------------- conversions ----------------

__global__ void k_cast_bf16(const float* __restrict__ in, unsigned short* __restrict__ out, int n4) {
    int i = blockIdx.x * 256 + threadIdx.x;
    if (i >= n4) return;
    float4 v = ((const float4*)in)[i];
    ushortx4 o;
    o[0] = f2bf(v.x); o[1] = f2bf(v.y); o[2] = f2bf(v.z); o[3] = f2bf(v.w);
    *(ushortx4*)&out[i * 4] = o;
}

// out[n][k] = bf16(in[k][n]); in is K x N fp32. grid (N/32, K/32), block (32,8)
__global__ void k_transpose_bf16(const float* __restrict__ in, unsigned short* __restrict__ out,
                                 int K, int N) {
    __shared__ float t[32][33];
    int nb = blockIdx.x * 32, kb = blockIdx.y * 32;
    int tx = threadIdx.x, ty = threadIdx.y;
#pragma unroll
    for (int i = 0; i < 4; ++i) {
        int k = kb + ty + i * 8;
        t[ty + i * 8][tx] = in[(size_t)k * N + nb + tx];
    }
    __syncthreads();
#pragma unroll
    for (int i = 0; i < 4; ++i) {
        int nrow = nb + ty + i * 8;
        out[(size_t)nrow * K + kb + tx] = f2bf(t[tx][ty + i * 8]);
    }
}

__global__ void k_add2(const float* __restrict__ a, const float* __restrict__ b,
                       float* __restrict__ o, int n) {
    int i = blockIdx.x * 256 + threadIdx.x;
    if (i < n) o[i] = a[i] + b[i];
}

// x_b[n][d] = bf16(emb[x_ids[n]][d]), row 0 of emb forced to 0
__global__ void k_gather_x(const int* __restrict__ ids, const float* __restrict__ emb,
                           unsigned short* __restrict__ xb) {
    int i = blockIdx.x * 256 + threadIdx.x;   // over NN*64
    int n = i >> 6, d4 = (i & 63) << 2;
    int id = ids[n];
    float4 v = make_float4(0.f, 0.f, 0.f, 0.f);
    if (id != 0) v = *(const float4*)&emb[(size_t)id * HD + d4];
    ushortx4 o;
    o[0] = f2bf(v.x); o[1] = f2bf(v.y); o[2] = f2bf(v.z); o[3] = f2bf(v.w);
    *(ushortx4*)&xb[(size_t)n * HD + d4] = o;
}

// ---------------- GEMM: C(MxN) = A(MxK bf16) * B^T  (B given as N x K bf16) ----------------

template <bool OUT_BF16, bool HAS_BIAS>
__global__ __launch_bounds__(256, 2) void k_gemm_bt(
    const unsigned short* __restrict__ A, const unsigned short* __restrict__ B,
    void* __restrict__ C, const float* __restrict__ bias, int M, int Nn, int K) {
    constexpr int LDT = 56;
    __shared__ unsigned short As[128 * LDT];
    __shared__ unsigned short Bs[128 * LDT];
    int tid = threadIdx.x;
    int wave = tid >> 6, lane = tid & 63;
    int q = lane >> 4, c16 = lane & 15;
    long m0 = (long)blockIdx.x * 128;
    long n0 = (long)blockIdx.y * 128;
    int wm = (wave & 1) << 6, wn = (wave >> 1) << 6;
    floatx4 acc[4][4] = {};
    int lrow = tid >> 2;
    int lk = (tid & 3) << 3;
    const unsigned short* Arow0 = A + (m0 + lrow) * K + lk;
    const unsigned short* Arow1 = A + (m0 + 64 + lrow) * K + lk;
    long nb0 = n0 + lrow;      if (nb0 >= Nn) nb0 = Nn - 1;
    long nb1 = n0 + 64 + lrow; if (nb1 >= Nn) nb1 = Nn - 1;
    const unsigned short* Brow0 = B + nb0 * K + lk;
    const unsigned short* Brow1 = B + nb1 * K + lk;

    for (int k0 = 0; k0 < K; k0 += 32) {
        ushortx8 a0 = *(const ushortx8*)(Arow0 + k0);
        ushortx8 a1 = *(const ushortx8*)(Arow1 + k0);
        ushortx8 b0 = *(const ushortx8*)(Brow0 + k0);
        ushortx8 b1 = *(const ushortx8*)(Brow1 + k0);
        __syncthreads();
        *(ushortx8*)&As[lrow * LDT + lk] = a0;
        *(ushortx8*)&As[(64 + lrow) * LDT + lk] = a1;
        *(ushortx8*)&Bs[lrow * LDT + lk] = b0;
        *(ushortx8*)&Bs[(64 + lrow) * LDT + lk] = b1;
        __syncthreads();
        shortx8 af[4], bfr[4];
#pragma unroll
        for (int mt = 0; mt < 4; ++mt)
            af[mt] = *(const shortx8*)&As[(wm + mt * 16 + c16) * LDT + q * 8];
#pragma unroll
        for (int nt = 0; nt < 4; ++nt)
            bfr[nt] = *(const shortx8*)&Bs[(wn + nt * 16 + c16) * LDT + q * 8];
#pragma unroll
        for (int mt = 0; mt < 4; ++mt)
#pragma unroll
            for (int nt = 0; nt < 4; ++nt)
                acc[mt][nt] = __builtin_amdgcn_mfma_f32_16x16x32_bf16(af[mt], bfr[nt], acc[mt][nt], 0, 0, 0);
    }
#pragma unroll
    for (int mt = 0; mt < 4; ++mt) {
        long row_base = m0 + wm + mt * 16 + q * 4;
#pragma unroll
        for (int nt = 0; nt < 4; ++nt) {
            long col = n0 + wn + nt * 16 + c16;
            if (col >= Nn) continue;
            float bv = HAS_BIAS ? bias[col] : 0.0f;
#pragma unroll
            for (int r = 0; r < 4; ++r) {
                float v = acc[mt][nt][r] + bv;
                long idx = (row_base + r) * (long)Nn + col;
                if (OUT_BF16) ((unsigned short*)C)[idx] = f2bf(v);
                else          ((float*)C)[idx] = v;
            }
        }
    }
}

// ---------------- attention dots ----------------

__global__ void k_alpha1(const unsigned short* __restrict__ h1b, const float* __restrict__ asrc,
                         const float* __restrict__ adst, float* __restrict__ als,
                         float* __restrict__ ald) {
    int n = blockIdx.x, t = threadIdx.x;
    ushortx8 hv = *(const ushortx8*)&h1b[(size_t)n * 2048 + t * 8];
    float s = 0.f, d = 0.f;
#pragma unroll
    for (int j = 0; j < 8; ++j) {
        float f = bf2f(hv[j]);
        s += f * asrc[t * 8 + j];
        d += f * adst[t * 8 + j];
    }
    for (int o = 16; o; o >>= 1) { s += __shfl_down(s, o, 32); d += __shfl_down(d, o, 32); }
    if ((t & 31) == 0) { als[n * 8 + (t >> 5)] = s; ald[n * 8 + (t >> 5)] = d; }
}

__global__ void k_alpha2(const unsigned short* __restrict__ x2b, const float* __restrict__ asrc,
                         const float* __restrict__ adst, float* __restrict__ als,
                         float* __restrict__ ald) {
    int n = blockIdx.x, t = threadIdx.x;
    ushortx4 hv = *(const ushortx4*)&x2b[(size_t)n * 256 + t * 4];
    float s = 0.f, d = 0.f;
#pragma unroll
    for (int j = 0; j < 4; ++j) {
        float f = bf2f(hv[j]);
        s += f * asrc[t * 4 + j];
        d += f * adst[t * 4 + j];
    }
    for (int o = 32; o; o >>= 1) { s += __shfl_down(s, o, 64); d += __shfl_down(d, o, 64); }
    if (t == 0) { als[n] = s; ald[n] = d; }
}

// ---------------- CSR build ----------------

__global__ void k_deg_init(int* __restrict__ deg) {
    int i = blockIdx.x * 256 + threadIdx.x;
    if (i < NN) deg[i] = 1;
}
__global__ void k_deg_count(const int* __restrict__ ei, int* __restrict__ deg) {
    int e = blockIdx.x * 256 + threadIdx.x;
    if (e < NE) atomicAdd(&deg[ei[NE + e]], 1);
}
__global__ void k_scan(const int* __restrict__ deg, int* __restrict__ row_start,
                       int* __restrict__ cursor) {
    __shared__ int s[1024];
    int t = threadIdx.x;
    int base = t * 16;
    int loc[16]; int sum = 0;
#pragma unroll
    for (int i = 0; i < 16; ++i) { loc[i] = deg[base + i]; sum += loc[i]; }
    s[t] = sum;
    __syncthreads();
    for (int o = 1; o < 1024; o <<= 1) {
        int v = (t >= o) ? s[t - o] : 0;
        __syncthreads();
        s[t] += v;
        __syncthreads();
    }
    int ex = s[t] - sum;
#pragma unroll
    for (int i = 0; i < 16; ++i) {
        row_start[base + i] = ex;
        cursor[base + i] = ex;
        ex += loc[i];
    }
    if (t == 0) row_start[NN] = NTOT;
}
__global__ void k_fill(const int* __restrict__ ei, int* __restrict__ cursor,
                       int* __restrict__ csr_src) {
    int e = blockIdx.x * 256 + threadIdx.x;
    if (e >= NTOT) return;
    int s, d;
    if (e < NE) { s = ei[e]; d = ei[NE + e]; }
    else        { s = e - NE; d = s; }
    int p = atomicAdd(&cursor[d], 1);
    csr_src[p] = s;
}

// ---------------- GAT aggregation ----------------

__global__ __launch_bounds__(256) void k_agg1(
    const int* __restrict__ row_start, const int* __restrict__ csr_src,
    const float* __restrict__ als, const float* __restrict__ ald,
    const unsigned short* __restrict__ h1b, const float* __restrict__ b1,
    unsigned short* __restrict__ out1b) {
    int n = blockIdx.x, t = threadIdx.x;
    int rs = row_start[n];
    int deg = row_start[n + 1] - rs;
    __shared__ float sm[8], sz[8], sad[8];
    if (t < 8) sad[t] = ald[n * 8 + t];
    __syncthreads();
    int hh = t >> 5, ii = t & 31;
    float adh = sad[hh];
    float lm = -1e30f;
    for (int i = ii; i < deg; i += 32) {
        int s = csr_src[rs + i];
        float e = als[s * 8 + hh] + adh;
        e = e >= 0.f ? e : 0.2f * e;
        lm = fmaxf(lm, e);
    }
    for (int o = 16; o; o >>= 1) lm = fmaxf(lm, __shfl_down(lm, o, 32));
    if (ii == 0) sm[hh] = lm;
    __syncthreads();
    float mh = sm[hh];
    float lz = 0.f;
    for (int i = ii; i < deg; i += 32) {
        int s = csr_src[rs + i];
        float e = als[s * 8 + hh] + adh;
        e = e >= 0.f ? e : 0.2f * e;
        lz += expf(e - mh);
    }
    for (int o = 16; o; o >>= 1) lz += __shfl_down(lz, o, 32);
    if (ii == 0) sz[hh] = lz;
    __syncthreads();
    float inv_z = 1.0f / (sz[hh] + 1e-16f);
    float acc[8] = {0.f, 0.f, 0.f, 0.f, 0.f, 0.f, 0.f, 0.f};
    for (int i = 0; i < deg; ++i) {
        int s = csr_src[rs + i];
        float e = als[s * 8 + hh] + adh;
        e = e >= 0.f ? e : 0.2f * e;
        float w = expf(e - mh) * inv_z;
        ushortx8 hv = *(const ushortx8*)&h1b[(size_t)s * 2048 + t * 8];
#pragma unroll
        for (int j = 0; j < 8; ++j) acc[j] += w * bf2f(hv[j]);
    }
    ushortx8 o8;
#pragma unroll
    for (int j = 0; j < 8; ++j) {
        float v = acc[j] + b1[t * 8 + j];
        v = v > 0.f ? v : expm1f(v);
        o8[j] = f2bf(v);
    }
    *(ushortx8*)&out1b[(size_t)n * 2048 + t * 8] = o8;
}

__global__ void k_agg2(const int* __restrict__ row_start, const int* __restrict__ csr_src,
                       const float* __restrict__ als, const float* __restrict__ ald,
                       const unsigned short* __restrict__ x2b, const float* __restrict__ b2,
                       unsigned short* __restrict__ out2b) {
    int n = blockIdx.x, t = threadIdx.x;
    int rs = row_start[n];
    int deg = row_start[n + 1] - rs;
    float adn = ald[n];
    float lm = -1e30f;
    for (int i = t; i < deg; i += 64) {
        float e = als[csr_src[rs + i]] + adn;
        e = e >= 0.f ? e : 0.2f * e;
        lm = fmaxf(lm, e);
    }
    for (int o = 32; o; o >>= 1) lm = fmaxf(lm, __shfl_down(lm, o, 64));
    float mh = __shfl(lm, 0, 64);
    float lz = 0.f;
    for (int i = t; i < deg; i += 64) {
        float e = als[csr_src[rs + i]] + adn;
        e = e >= 0.f ? e : 0.2f * e;
        lz += expf(e - mh);
    }
    for (int o = 32; o; o >>= 1) lz += __shfl_down(lz, o, 64);
    float zz = __shfl(lz, 0, 64);
    float inv_z = 1.0f / (zz + 1e-16f);
    float acc[4] = {0.f, 0.f, 0.f, 0.f};
    for (int i = 0; i < deg; ++i) {
        int s = csr_src[rs + i];
        float e = als[s] + adn;
        e = e >= 0.f ? e : 0.2f * e;
        float w = expf(e - mh) * inv_z;
        ushortx4 hv = *(const ushortx4*)&x2b[(size_t)s * 256 + t * 4];
#pragma unroll
        for (int j = 0; j < 4; ++j) acc[j] += w * bf2f(hv[j]);
    }
    ushortx4 o4;
#pragma unroll
    for (int j = 0; j < 4; ++j) o4[j] = f2bf(acc[j] + b2[t * 4 + j]);
    *(ushortx4*)&out2b[(size_t)n * 256 + t * 4] = o4;
}

// ---------------- LSTM recurrence ----------------
// 16 blocks x 512 threads (8 waves). Block owns 16 batch rows, 64 steps in-kernel.
// Wave w owns h-cols [w*32, w*32+32) for all 4 gates (128 gate-cols).
// Whh (512KB bf16) residency per 32-wide K chunk (8 chunks):
//   chunks 3..6 -> registers (128 VGPR/wave), chunks 1..2 -> LDS (128KB),
//   chunks 0,7 -> streamed from L2 each step (prefetched ahead of use).
// h state double-buffered in LDS -> ONE barrier per step; epilogue VALU of one
// wave overlaps MFMA of others.

__global__ __launch_bounds__(512, 2) void k_lstm(const float* __restrict__ Xg,
                                                 const unsigned short* __restrict__ Whhb,
                                                 unsigned short* __restrict__ hTb) {
    __shared__ unsigned short blds[64 * 1024];     // 128 KB: frag (wave*8+fg)*2+j, 512 shorts each
    __shared__ unsigned short hb2[2 * 16 * 264];   // double-buffered h, row stride 264 shorts

    int tid = threadIdx.x;
    int wave = tid >> 6, lane = tid & 63;
    int q = lane >> 4, c16 = lane & 15;
    int r0 = blockIdx.x * 16;

    // per-lane base pointers for the 8 fragment columns this wave owns
    const unsigned short* wb[8];
#pragma unroll
    for (int g = 0; g < 4; ++g)
#pragma unroll
        for (int ct = 0; ct < 2; ++ct)
            wb[g * 2 + ct] = Whhb + (size_t)(g * 256 + wave * 32 + ct * 16 + c16) * 256 + q * 8;

    // load register-resident chunks 3..6 and fill LDS chunks 1..2
    shortx8 breg[8][4];
#pragma unroll
    for (int fg = 0; fg < 8; ++fg) {
#pragma unroll
        for (int j = 0; j < 4; ++j)
            breg[fg][j] = *(const shortx8*)(wb[fg] + (3 + j) * 32);
#pragma unroll
        for (int j = 0; j < 2; ++j)
            *(shortx8*)&blds[((wave * 8 + fg) * 2 + j) * 512 + lane * 8] =
                *(const shortx8*)(wb[fg] + (1 + j) * 32);
    }

    // zero h buffer 0
    for (int i = tid; i < 16 * 264; i += 512) hb2[i] = 0;
    float cst[2][4] = {};

    // prefetch streamed chunk 0 for step 0
    shortx8 sa[8];
#pragma unroll
    for (int fg = 0; fg < 8; ++fg) sa[fg] = *(const shortx8*)(wb[fg]);

    __syncthreads();

    for (int t = 0; t < SL; ++t) {
        int p = t & 1;
        floatx4 acc[8] = {};
        shortx8 sb[8];
#pragma unroll
        for (int k0 = 0; k0 < 8; ++k0) {
            shortx8 a = *(const shortx8*)&hb2[p * 4224 + c16 * 264 + k0 * 32 + q * 8];
            if (k0 == 1) {   // issue streamed chunk 7 (consumed at k0==7)
#pragma unroll
                for (int fg = 0; fg < 8; ++fg) sb[fg] = *(const shortx8*)(wb[fg] + 7 * 32);
            }
#pragma unroll
            for (int fg = 0; fg < 8; ++fg) {
                shortx8 b = (k0 == 0) ? sa[fg]
                          : (k0 <= 2) ? *(const shortx8*)&blds[((wave * 8 + fg) * 2 + (k0 - 1)) * 512 + lane * 8]
                          : (k0 <= 6) ? breg[fg][k0 - 3]
                                      : sb[fg];
                acc[fg] = __builtin_amdgcn_mfma_f32_16x16x32_bf16(a, b, acc[fg], 0, 0, 0);
            }
        }
        // prefetch streamed chunk 0 for next step (covered by epilogue + barrier)
#pragma unroll
        for (int fg = 0; fg < 8; ++fg) sa[fg] = *(const shortx8*)(wb[fg]);

        // epilogue: gates -> c,h; write h into the other buffer
#pragma unroll
        for (int ct = 0; ct < 2; ++ct) {
#pragma unroll
            for (int r = 0; r < 4; ++r) {
                const float* xp = Xg + ((size_t)(r0 + q * 4 + r) * SL + t) * 1024 + wave * 32 + ct * 16 + c16;
                float gi = acc[0 * 2 + ct][r] + xp[0];
                float gf = acc[1 * 2 + ct][r] + xp[256];
                float gg = acc[2 * 2 + ct][r] + xp[512];
                float go = acc[3 * 2 + ct][r] + xp[768];
                float si = __builtin_amdgcn_rcpf(1.f + __expf(-gi));
                float sf = __builtin_amdgcn_rcpf(1.f + __expf(-gf));
                float so = __builtin_amdgcn_rcpf(1.f + __expf(-go));
                float tg = 1.f - 2.f * __builtin_amdgcn_rcpf(1.f + __expf(2.f * gg));
                float c = sf * cst[ct][r] + si * tg;
                cst[ct][r] = c;
                float tc = 1.f - 2.f * __builtin_amdgcn_rcpf(1.f + __expf(2.f * c));
                hb2[(p ^ 1) * 4224 + (q * 4 + r) * 264 + wave * 32 + ct * 16 + c16] = f2bf(so * tc);
            }
        }
        __syncthreads();
    }
    // SL even -> final h is in buffer 0
    for (int i = tid; i < 16 * 256; i += 512) {
        int row = i >> 8, col = i & 255;
        hTb[(size_t)(r0 + row) * 256 + col] = hb2[row * 264 + col];
    }
}

// ---------------- launch ----------------

extern "C" void kernel_launch(void* const* d_in, const int* in_sizes, int n_in,
                              void* d_out, int out_size, void* d_ws, size_t ws_size,
                              hipStream_t stream) {
    const int*   x_ids = (const int*)d_in[0];
    const int*   ei    = (const int*)d_in[1];
    const float* emb   = (const float*)d_in[3];
    const float* W1    = (const float*)d_in[4];
    const float* as1w  = (const float*)d_in[5];
    const float* ad1w  = (const float*)d_in[6];
    const float* b1    = (const float*)d_in[7];
    const float* W2    = (const float*)d_in[8];
    const float* as2w  = (const float*)d_in[9];
    const float* ad2w  = (const float*)d_in[10];
    const float* b2    = (const float*)d_in[11];
    const float* Wih   = (const float*)d_in[12];
    const float* Whh   = (const float*)d_in[13];
    const float* bih   = (const float*)d_in[14];
    const float* bhh   = (const float*)d_in[15];
    const float* Wp    = (const float*)d_in[16];
    const float* bp    = (const float*)d_in[17];

    char* ws = (char*)d_ws;
    size_t off = 0;
    auto alloc = [&](size_t bytes) -> void* {
        void* p = ws + off;
        off += (bytes + 255) & ~(size_t)255;
        return p;
    };
    unsigned short* h1b   = (unsigned short*)alloc((size_t)NN * 2048 * 2);  // reused as Xg
    float*          Xg    = (float*)h1b;
    unsigned short* out1b = (unsigned short*)alloc((size_t)NN * 2048 * 2);
    unsigned short* xb    = (unsigned short*)alloc((size_t)NN * 256 * 2);
    unsigned short* x2b   = (unsigned short*)alloc((size_t)NN * 256 * 2);
    unsigned short* out2b = (unsigned short*)alloc((size_t)NN * 256 * 2);
    unsigned short* W1t   = (unsigned short*)alloc((size_t)2048 * 256 * 2);
    unsigned short* W2t   = (unsigned short*)alloc((size_t)256 * 2048 * 2);
    unsigned short* Wihb  = (unsigned short*)alloc((size_t)1024 * 256 * 2);
    unsigned short* Whhb  = (unsigned short*)alloc((size_t)1024 * 256 * 2);
    unsigned short* Wpb   = (unsigned short*)alloc((size_t)37000 * 256 * 2);
    float*          bb    = (float*)alloc(1024 * 4);
    float*          als1  = (float*)alloc((size_t)NN * 8 * 4);
    float*          ald1  = (float*)alloc((size_t)NN * 8 * 4);
    float*          als2  = (float*)alloc((size_t)NN * 4);
    float*          ald2  = (float*)alloc((size_t)NN * 4);
    unsigned short* hTb   = (unsigned short*)alloc((size_t)256 * 256 * 2);
    int* deg       = (int*)alloc((size_t)NN * 4);
    int* row_start = (int*)alloc((size_t)(NN + 1) * 4);
    int* cursor    = (int*)alloc((size_t)NN * 4);
    int* csr_src   = (int*)alloc((size_t)NTOT * 4);
    (void)ws_size; (void)in_sizes; (void)n_in; (void)out_size;

    // weight prep
    k_transpose_bf16<<<dim3(2048 / 32, 256 / 32), dim3(32, 8), 0, stream>>>(W1, W1t, 256, 2048);
    k_transpose_bf16<<<dim3(256 / 32, 2048 / 32), dim3(32, 8), 0, stream>>>(W2, W2t, 2048, 256);
    k_cast_bf16<<<(262144 / 4 + 255) / 256, 256, 0, stream>>>(Wih, Wihb, 262144 / 4);
    k_cast_bf16<<<(262144 / 4 + 255) / 256, 256, 0, stream>>>(Whh, Whhb, 262144 / 4);
    k_cast_bf16<<<(9472000 / 4 + 255) / 256, 256, 0, stream>>>(Wp, Wpb, 9472000 / 4);
    k_add2<<<4, 256, 0, stream>>>(bih, bhh, bb, 1024);

    // CSR
    k_deg_init<<<NN / 256, 256, 0, stream>>>(deg);
    k_deg_count<<<NE / 256, 256, 0, stream>>>(ei, deg);
    k_scan<<<1, 1024, 0, stream>>>(deg, row_start, cursor);
    k_fill<<<(NTOT + 255) / 256, 256, 0, stream>>>(ei, cursor, csr_src);

    // embedding gather
    k_gather_x<<<NN * 64 / 256, 256, 0, stream>>>(x_ids, emb, xb);

    // GAT layer 1
    k_gemm_bt<true, false><<<dim3(NN / 128, 2048 / 128), 256, 0, stream>>>(
        xb, W1t, h1b, nullptr, NN, 2048, 256);
    k_alpha1<<<NN, 256, 0, stream>>>(h1b, as1w, ad1w, als1, ald1);
    k_agg1<<<NN, 256, 0, stream>>>(row_start, csr_src, als1, ald1, h1b, b1, out1b);

    // GAT layer 2
    k_gemm_bt<true, false><<<dim3(NN / 128, 256 / 128), 256, 0, stream>>>(
        out1b, W2t, x2b, nullptr, NN, 256, 2048);
    k_alpha2<<<NN, 64, 0, stream>>>(x2b, as2w, ad2w, als2, ald2);
    k_agg2<<<NN, 64, 0, stream>>>(row_start, csr_src, als2, ald2, x2b, b2, out2b);

    // LSTM: Xg = out2 @ Wih^T + (bih + bhh)
    k_gemm_bt<false, true><<<dim3(NN / 128, 1024 / 128), 256, 0, stream>>>(
        out2b, Wihb, Xg, bb, NN, 1024, 256);
    k_lstm<<<16, 512, 0, stream>>>(Xg, Whhb, hTb);

    // final projection
    k_gemm_bt<false, true><<<dim3(256 / 128, (37000 + 127) / 128), 256, 0, stream>>>(
        hTb, Wpb, (float*)d_out, bp, 256, 37000, 256);
}